// Round 11
// baseline (179.327 us; speedup 1.0000x reference)
//
#include <hip/hip_runtime.h>
#include <hip/hip_bf16.h>

// MyMSA: B=4 S=2048 D=1024 H=16 DH=64. fp32 in/out. bf16 MFMA, fp32 accum.
//
// R18: BARRIER-FREE attn via wave-private LDS staging. Diagnosis (R13/R14,
// 8 variants all ~80+-4us): MFMA blocks its wave; the per-tile barrier
// keeps the 2 waves/SIMD in lockstep so neither fills the other's
// QK->exp2->PV stalls (~25% dead cycles). Change: each wave stages its OWN
// KT=32 K/V tile into a private 9.5KB LDS region; zero __syncthreads in
// the kernel. Same-wave DS ordering (store->read) is handled by compiler
// lgkmcnt; no cross-wave LDS sharing. Costs bounded: 4x K/V L2 reads
// (1.07GB, K/V 512KB/bh L2-resident), 2x LDS writes/wave (~50K cy/SIMD
// < matrix ~70K), ~8-way write conflicts on 8 instrs (accepted).
// qkv v2 kept (R17: cut ~13.5us; near its ~13us memory floor).
// Accounting (11 rounds): attn ~80, qkv ~15, fixed harness residue ~74.
// Standing lessons: no direct-from-global operand frags (R8/R9); spill
// cliff ~190+ live but lb(256,2)+AGPR split handles ~200 (R11); occupancy
// /barrier-count/KT/qt/MFMA-shape/T15 all null inside the barriered
// structure (R10-R15). Falsifier here: dur>=76 => plateau is wave-internal
// => declare.

typedef unsigned short u16;
typedef unsigned int   u32;
typedef float  f32x4  __attribute__((ext_vector_type(4)));
typedef __bf16 bf16x4 __attribute__((ext_vector_type(4)));
typedef __bf16 bf16x8 __attribute__((ext_vector_type(8)));

#define NB 4
#define SS 2048
#define DDIM 1024
#define NH 16
#define DH 64

static __device__ __forceinline__ float fexp2(float x) {
#if __has_builtin(__builtin_amdgcn_exp2f)
    return __builtin_amdgcn_exp2f(x);
#else
    return exp2f(x);
#endif
}
static __device__ __forceinline__ bf16x4 cvt4(f32x4 v) {
    return __builtin_convertvector(v, bf16x4);   // v_cvt_pk_bf16_f32 on gfx950
}
static __device__ __forceinline__ bf16x8 cvt8(f32x4 lo, f32x4 hi) {
    return __builtin_shufflevector(cvt4(lo), cvt4(hi), 0, 1, 2, 3, 4, 5, 6, 7);
}

// ---------------- Kernel 1: QKV projection v2 (R17 verbatim) -------------
// grid: 64 * 16 = 1024 blocks (bh = bid&63 -> co-XCD with attn), 256 thr.
#define WST 72   // W_lds row stride (u16): 144B

__global__ __launch_bounds__(256) void qkv_kernel(
        const float* __restrict__ x,
        const float* __restrict__ Wq, const float* __restrict__ bq,
        const float* __restrict__ Wk, const float* __restrict__ bk,
        const float* __restrict__ Wv, const float* __restrict__ bv,
        u16* __restrict__ Qw, u16* __restrict__ Kw, u16* __restrict__ Vt) {
    __shared__ __align__(16) u16 W_lds[3 * DH * WST];   // 27.6 KB

    const int tid  = threadIdx.x;
    const int w    = tid >> 6;
    const int lane = tid & 63;
    const int quad = lane >> 4;
    const int c    = lane & 15;
    const int bid  = blockIdx.x;
    const int bh   = bid & 63;
    const int s0   = (bid >> 6) * 128;
    const int b    = bh >> 4, h = bh & 15;

    // stage W fp32 -> bf16 into LDS (W total 786KB -> L2-resident re-reads)
    {
        const float* Wsrc[3] = {Wq + h*DH*DH, Wk + h*DH*DH, Wv + h*DH*DH};
        #pragma unroll
        for (int j = 0; j < 6; ++j) {
            const int m = j >> 1;
            const int chunk = ((j & 1) << 8) + tid;      // 0..511 within mat
            const float* src = Wsrc[m] + chunk * 8;
            f32x4 lo = *(const f32x4*)src;
            f32x4 hi = *(const f32x4*)(src + 4);
            const int row = chunk >> 3, c8 = chunk & 7;
            *(bf16x8*)&W_lds[(m*DH + row) * WST + c8*8] = cvt8(lo, hi);
        }
    }

    // x loads for BOTH groups issued before the barrier: 8 independent
    // dwordx4 in flight -> one latency exposure for the whole block.
    const int sbA = s0 + w*32;          // group A tokens: sbA + c
    const int sbB = sbA + 16;           // group B tokens: sbB + c
    const float* xrA = x + ((size_t)(b * SS + sbA + c)) * DDIM + h * DH;
    const float* xrB = x + ((size_t)(b * SS + sbB + c)) * DDIM + h * DH;
    f32x4 a0 = *(const f32x4*)(xrA + quad*8);
    f32x4 a1 = *(const f32x4*)(xrA + quad*8 + 4);
    f32x4 a2 = *(const f32x4*)(xrA + 32 + quad*8);
    f32x4 a3 = *(const f32x4*)(xrA + 32 + quad*8 + 4);
    f32x4 b0 = *(const f32x4*)(xrB + quad*8);
    f32x4 b1 = *(const f32x4*)(xrB + quad*8 + 4);
    f32x4 b2 = *(const f32x4*)(xrB + 32 + quad*8);
    f32x4 b3 = *(const f32x4*)(xrB + 32 + quad*8 + 4);

    f32x4 biasQK[2][4];
    float biasV[4];
    #pragma unroll
    for (int mt = 0; mt < 4; ++mt) {
        biasQK[0][mt] = *(const f32x4*)(bq + h*DH + mt*16 + quad*4);
        biasQK[1][mt] = *(const f32x4*)(bk + h*DH + mt*16 + quad*4);
        biasV[mt] = bv[h*DH + mt*16 + c];
    }

    __syncthreads();

    bf16x8 xbA[2] = { cvt8(a0, a1), cvt8(a2, a3) };
    bf16x8 xbB[2] = { cvt8(b0, b1), cvt8(b2, b3) };

    const size_t qkbase = (size_t)bh * SS * DH;
    const size_t vtbase = (size_t)bh * DH * SS;

    // K-row permutation (R6/R11 16-wide form)
    const int srowA = sbA + c, srowB = sbB + c;
    const int tqA = srowA & 31, tqB = srowB & 31;
    const int sKA = (srowA & ~31) | ((tqA & 4) << 2) | ((tqA >> 3) << 2) | (tqA & 3);
    const int sKB = (srowB & ~31) | ((tqB & 4) << 2) | ((tqB >> 3) << 2) | (tqB & 3);

    // Q, K: swapped operands (A = W frag from LDS, B = X^T frag)
    #pragma unroll
    for (int m = 0; m < 2; ++m) {
        const float scale = (m == 0) ? 0.18033688f : 1.0f;  // 0.125*log2(e)
        u16* baseA = (m == 0 ? Qw : Kw) + qkbase + (size_t)(m == 0 ? srowA : sKA) * DH;
        u16* baseB = (m == 0 ? Qw : Kw) + qkbase + (size_t)(m == 0 ? srowB : sKB) * DH;
        #pragma unroll
        for (int mt = 0; mt < 4; ++mt) {
            const bf16x8 w0 = *(const bf16x8*)&W_lds[(m*DH + mt*16 + c) * WST + quad*8];
            const bf16x8 w1 = *(const bf16x8*)&W_lds[(m*DH + mt*16 + c) * WST + 32 + quad*8];
            f32x4 accA = {0.f, 0.f, 0.f, 0.f};
            accA = __builtin_amdgcn_mfma_f32_16x16x32_bf16(w0, xbA[0], accA, 0, 0, 0);
            accA = __builtin_amdgcn_mfma_f32_16x16x32_bf16(w1, xbA[1], accA, 0, 0, 0);
            f32x4 accB = {0.f, 0.f, 0.f, 0.f};
            accB = __builtin_amdgcn_mfma_f32_16x16x32_bf16(w0, xbB[0], accB, 0, 0, 0);
            accB = __builtin_amdgcn_mfma_f32_16x16x32_bf16(w1, xbB[1], accB, 0, 0, 0);
            f32x4 vA = (accA + biasQK[m][mt]) * scale;
            f32x4 vB = (accB + biasQK[m][mt]) * scale;
            *(bf16x4*)(baseA + mt*16 + quad*4) = cvt4(vA);   // b64 store
            *(bf16x4*)(baseB + mt*16 + quad*4) = cvt4(vB);
        }
    }
    // V: non-swapped (A = X frag, B = W frag) -> C rows = tokens
    #pragma unroll
    for (int nt = 0; nt < 4; ++nt) {
        const bf16x8 w0 = *(const bf16x8*)&W_lds[(2*DH + nt*16 + c) * WST + quad*8];
        const bf16x8 w1 = *(const bf16x8*)&W_lds[(2*DH + nt*16 + c) * WST + 32 + quad*8];
        f32x4 accA = {0.f, 0.f, 0.f, 0.f};
        accA = __builtin_amdgcn_mfma_f32_16x16x32_bf16(xbA[0], w0, accA, 0, 0, 0);
        accA = __builtin_amdgcn_mfma_f32_16x16x32_bf16(xbA[1], w1, accA, 0, 0, 0);
        f32x4 accB = {0.f, 0.f, 0.f, 0.f};
        accB = __builtin_amdgcn_mfma_f32_16x16x32_bf16(xbB[0], w0, accB, 0, 0, 0);
        accB = __builtin_amdgcn_mfma_f32_16x16x32_bf16(xbB[1], w1, accB, 0, 0, 0);
        f32x4 vA = accA + biasV[nt];
        f32x4 vB = accB + biasV[nt];
        u16* dstA = Vt + vtbase + (size_t)(nt*16 + c) * SS + sbA + quad*4;
        u16* dstB = Vt + vtbase + (size_t)(nt*16 + c) * SS + sbB + quad*4;
        *(bf16x4*)dstA = cvt4(vA);                           // b64 along s
        *(bf16x4*)dstB = cvt4(vB);
    }
}

// ---------------- Kernel 2: flash attention, barrier-free ----------------
// grid: 64 * 8 = 512 blocks, 256 threads (4 waves x 64 q = 4 qt). KT=32.
// Each wave owns a private K/V staging region; NO __syncthreads anywhere.
#define KT 32
#define KST 72    // K row stride (u16): 144B (16B-aligned; 2-way-free reads)
#define VST 40    // V row stride (u16): 80B (16B-aligned; 2-way-free reads)
#define WKV (32*KST + 64*VST)   // 4864 u16 = 9728B per wave

__global__ __launch_bounds__(256, 2) void attn_kernel(
        const u16* __restrict__ Qw, const u16* __restrict__ Kw,
        const u16* __restrict__ Vt, float* __restrict__ out) {
    __shared__ __align__(16) u16 lds[4 * WKV];   // 38.9 KB, wave-private quarters

    const int tid  = threadIdx.x;
    const int w    = tid >> 6;
    const int lane = tid & 63;
    const int quad = lane >> 4;
    const int c    = lane & 15;
    const int bid  = blockIdx.x;
    const int bh   = bid & 63;           // XCD swizzle: same bh -> same XCD
    const int q0   = (bid >> 6) * 256;
    const int qw   = q0 + w * 64;        // wave's 64 q-rows (4 qt)

    const u16* Qb = Qw + (size_t)bh * SS * DH;
    const u16* Kb = Kw + (size_t)bh * SS * DH;
    const u16* Vb = Vt + (size_t)bh * DH * SS;

    u16* wK = lds + w * WKV;             // private K tile: 32 rows x KST
    u16* wV = wK + 32 * KST;             // private V tile: 64 rows x VST

    // Q B-frags (n=q=c, k=d=quad*8+j)
    bf16x8 qf[4][2];
    #pragma unroll
    for (int qt = 0; qt < 4; ++qt) {
        const u16* qrow = Qb + (size_t)(qw + qt*16 + c) * DH;
        qf[qt][0] = *(const bf16x8*)(qrow + quad*8);
        qf[qt][1] = *(const bf16x8*)(qrow + 32 + quad*8);
    }

    f32x4 o[4][4];      // o[dt][qt]: O^T C-frags (col=q, row=d-local)
    f32x4 lacc[4];
    #pragma unroll
    for (int qt = 0; qt < 4; ++qt) {
        lacc[qt] = (f32x4){0.f, 0.f, 0.f, 0.f};
        #pragma unroll
        for (int dt = 0; dt < 4; ++dt) o[dt][qt] = (f32x4){0.f, 0.f, 0.f, 0.f};
    }

    bf16x8 ones8;
    { union { u16 u[8]; bf16x8 v; } one;
      #pragma unroll
      for (int i = 0; i < 8; ++i) one.u[i] = 0x3F80;
      ones8 = one.v; }

    // per-wave staging lane map:
    // K: 32 rows x 64 u16 -> 2 lanes/row, 32 u16 (4x uint4) each
    const int klr = lane >> 1;           // 0..31
    const int klc = (lane & 1) * 32;     // 0 | 32
    // V: 64 rows x 32 u16 -> 4 loads, row = 16p + (lane>>2), 8 u16 each
    const int vlr = lane >> 2;           // 0..15
    const int vlc = (lane & 3) * 8;      // 0..24

    // prologue: load tile 0 into registers
    uint4 kr0 = *(const uint4*)(Kb + (size_t)klr * DH + klc);
    uint4 kr1 = *(const uint4*)(Kb + (size_t)klr * DH + klc + 8);
    uint4 kr2 = *(const uint4*)(Kb + (size_t)klr * DH + klc + 16);
    uint4 kr3 = *(const uint4*)(Kb + (size_t)klr * DH + klc + 24);
    uint4 vr0 = *(const uint4*)(Vb + (size_t)( 0 + vlr) * SS + vlc);
    uint4 vr1 = *(const uint4*)(Vb + (size_t)(16 + vlr) * SS + vlc);
    uint4 vr2 = *(const uint4*)(Vb + (size_t)(32 + vlr) * SS + vlc);
    uint4 vr3 = *(const uint4*)(Vb + (size_t)(48 + vlr) * SS + vlc);

    #pragma unroll 1
    for (int t0 = 0; t0 < SS; t0 += KT) {
        // store tile t0 into OWN region (no barrier; same-wave DS order)
        *(uint4*)&wK[klr*KST + klc]      = kr0;
        *(uint4*)&wK[klr*KST + klc + 8]  = kr1;
        *(uint4*)&wK[klr*KST + klc + 16] = kr2;
        *(uint4*)&wK[klr*KST + klc + 24] = kr3;
        *(uint4*)&wV[( 0 + vlr)*VST + vlc] = vr0;
        *(uint4*)&wV[(16 + vlr)*VST + vlc] = vr1;
        *(uint4*)&wV[(32 + vlr)*VST + vlc] = vr2;
        *(uint4*)&wV[(48 + vlr)*VST + vlc] = vr3;

        // issue next-tile global loads (in flight across this tile's compute)
        int tn = t0 + KT; if (tn >= SS) tn = 0;    // wrap: harmless reload
        kr0 = *(const uint4*)(Kb + (size_t)(tn + klr) * DH + klc);
        kr1 = *(const uint4*)(Kb + (size_t)(tn + klr) * DH + klc + 8);
        kr2 = *(const uint4*)(Kb + (size_t)(tn + klr) * DH + klc + 16);
        kr3 = *(const uint4*)(Kb + (size_t)(tn + klr) * DH + klc + 24);
        vr0 = *(const uint4*)(Vb + (size_t)( 0 + vlr) * SS + tn + vlc);
        vr1 = *(const uint4*)(Vb + (size_t)(16 + vlr) * SS + tn + vlc);
        vr2 = *(const uint4*)(Vb + (size_t)(32 + vlr) * SS + tn + vlc);
        vr3 = *(const uint4*)(Vb + (size_t)(48 + vlr) * SS + tn + vlc);

        // fragment reads (compiler inserts lgkmcnt wait on own writes)
        bf16x8 kf0 = *(const bf16x8*)&wK[(     c)*KST +      quad*8];
        bf16x8 kf1 = *(const bf16x8*)&wK[(     c)*KST + 32 + quad*8];
        bf16x8 kf2 = *(const bf16x8*)&wK[(16 + c)*KST +      quad*8];
        bf16x8 kf3 = *(const bf16x8*)&wK[(16 + c)*KST + 32 + quad*8];
        bf16x8 vf0 = *(const bf16x8*)&wV[(     c)*VST + quad*8];
        bf16x8 vf1 = *(const bf16x8*)&wV[(16 + c)*VST + quad*8];
        bf16x8 vf2 = *(const bf16x8*)&wV[(32 + c)*VST + quad*8];
        bf16x8 vf3 = *(const bf16x8*)&wV[(48 + c)*VST + quad*8];

        __builtin_amdgcn_s_setprio(1);
        #pragma unroll
        for (int qt = 0; qt < 4; ++qt) {
            f32x4 sA = {0.f,0.f,0.f,0.f}, sB = {0.f,0.f,0.f,0.f};
            sA = __builtin_amdgcn_mfma_f32_16x16x32_bf16(kf0, qf[qt][0], sA, 0,0,0);
            sA = __builtin_amdgcn_mfma_f32_16x16x32_bf16(kf1, qf[qt][1], sA, 0,0,0);
            sB = __builtin_amdgcn_mfma_f32_16x16x32_bf16(kf2, qf[qt][0], sB, 0,0,0);
            sB = __builtin_amdgcn_mfma_f32_16x16x32_bf16(kf3, qf[qt][1], sB, 0,0,0);
            f32x4 eA, eB;
            #pragma unroll
            for (int r = 0; r < 4; ++r) { eA[r] = fexp2(sA[r]); eB[r] = fexp2(sB[r]); }
            bf16x8 pf = cvt8(eA, eB);
            o[0][qt] = __builtin_amdgcn_mfma_f32_16x16x32_bf16(vf0, pf, o[0][qt], 0,0,0);
            o[1][qt] = __builtin_amdgcn_mfma_f32_16x16x32_bf16(vf1, pf, o[1][qt], 0,0,0);
            o[2][qt] = __builtin_amdgcn_mfma_f32_16x16x32_bf16(vf2, pf, o[2][qt], 0,0,0);
            o[3][qt] = __builtin_amdgcn_mfma_f32_16x16x32_bf16(vf3, pf, o[3][qt], 0,0,0);
            lacc[qt] = __builtin_amdgcn_mfma_f32_16x16x32_bf16(ones8, pf, lacc[qt], 0,0,0);
        }
        __builtin_amdgcn_s_setprio(0);
    }

    // epilogue: lane holds token = qw + qt*16 + c, d = dt*16 + quad*4 + r
    const int b = bh >> 4, h = bh & 15;
    #pragma unroll
    for (int qt = 0; qt < 4; ++qt) {
        const float inv = 1.0f / lacc[qt][0];
        const int token = qw + qt*16 + c;
        float* orow = out + ((size_t)b * SS + token) * DDIM + h * DH;
        #pragma unroll
        for (int dt = 0; dt < 4; ++dt) {
            f32x4 vv = o[dt][qt] * inv;
            *(f32x4*)(orow + dt*16 + quad*4) = vv;
        }
    }
}

extern "C" void kernel_launch(void* const* d_in, const int* in_sizes, int n_in,
                              void* d_out, int out_size, void* d_ws, size_t ws_size,
                              hipStream_t stream) {
    const float* x  = (const float*)d_in[0];
    const float* Wq = (const float*)d_in[1];
    const float* bq = (const float*)d_in[2];
    const float* Wk = (const float*)d_in[3];
    const float* bk = (const float*)d_in[4];
    const float* Wv = (const float*)d_in[5];
    const float* bv = (const float*)d_in[6];

    // ws: Qw[bh][s][d], Kw[bh][s'][d] (s permuted per 32), Vt[bh][d][s]
    u16* Qw = (u16*)d_ws;
    u16* Kw = Qw + (size_t)NB * NH * SS * DH;
    u16* Vt = Kw + (size_t)NB * NH * SS * DH;

    qkv_kernel<<<64 * (SS / 128), 256, 0, stream>>>(
        x, Wq, bq, Wk, bk, Wv, bv, Qw, Kw, Vt);
    attn_kernel<<<64 * (SS / 256), 256, 0, stream>>>(Qw, Kw, Vt, (float*)d_out);
}